// Round 4
// baseline (246.967 us; speedup 1.0000x reference)
//
#include <hip/hip_runtime.h>

// NonMaxSuppression: 3x3 local max + thr>=0.6 + 10px border -> ordered (y,x) coords.
// Input fixed: (16,1,1536,1536) fp32.
// Pass1: barrier-free rolling-register NMS. 1024 blocks x 384 threads (= exactly
//        4 blocks/CU x 256 CU -> one balanced scheduling round, zero tail).
//        Block = 24 rows; thread = 4 aligned cols. ONE aligned float4/row + 2 wave
//        shuffles for the 6-wide halo (predicated scalar at wave edges); separable
//        v_max3 vertical window rolls in registers. u64 masks + per-block counts.
// Pass2 (fused scan+scatter): 1024 blocks x 576 threads, strips 1:1 with pass1.
//        Block offset from the 1024 counts (2 loads/thread + reduce). Replay masks
//        into LDS as packed (y|x<<16), then COALESCED write of both output streams.
//        Direct-scatter fallback past CAP keeps arbitrary inputs correct.
#define W 1536
#define H 1536
#define NB 16
#define NROWS (NB * H)          // 24576
#define SH 24                   // rows per strip (pass1 AND pass2)
#define NBLK (NROWS / SH)       // 1024
#define BLOCK1 384              // 1536/4 cols per thread
#define CPR 24                  // u64 chunks per row
#define NMASK (NROWS * CPR)     // 589824 u64 = 4.72 MB
#define BLOCK2 (SH * CPR)       // 576 threads = chunks per strip
#define NW2 (BLOCK2 / 64)       // 9 waves
#define CAP 5376                // staged items/block (21 KB LDS); expected ~4000
#define REP_THR 0.6f

__device__ __forceinline__ float max3f(float a, float b, float c) {
    return fmaxf(fmaxf(a, b), c);  // v_max3_f32
}

__global__ __launch_bounds__(BLOCK1) void nms_pass1(const float* __restrict__ in,
                                                    unsigned long long* __restrict__ masks,
                                                    unsigned int* __restrict__ counts) {
    const int t = threadIdx.x;
    const int lane = t & 63;
    const int wv = t >> 6;
    const int blk = blockIdx.x;
    const int r0 = blk * SH;                 // first output row (global)
    const int ytile = blk % (H / SH);        // strip index within image (1536/24=64)

    const int c0 = 4 * t;                    // aligned float4 column base
    // wave-edge halo columns (clamped; clamped lanes masked by colm)
    const int cl = (t == 0) ? 0 : c0 - 1;
    const int cr = (t == BLOCK1 - 1) ? (W - 1) : c0 + 4;

    // x-border nibble mask, valid x in [10, 1526); bit j <-> col 4t+j
    unsigned colm = 0xFu;
    if (t <= 1) colm = 0u;
    else if (t == 2) colm = 0xCu;
    if (t >= 382) colm = 0u;
    else if (t == 381) colm = 0x3u;

    auto rowp = [&](int i) {                 // input row rel i (rel 0 = r0-1), clamped
        int ir = r0 - 1 + i;
        ir = ir < 0 ? 0 : (ir >= NROWS ? NROWS - 1 : ir);
        return in + (size_t)ir * W;
    };

    // halo via wave shuffle: h[j] = max of cols c0+j-1 .. c0+j+1
    auto mkhalo = [&](float4 v, float lw, float rx) {
        float lw_all = __shfl_up(v.w, 1, 64);
        if (lane == 0) lw_all = lw;          // from predicated edge load
        float rx_all = __shfl_down(v.x, 1, 64);
        if (lane == 63) rx_all = rx;
        float4 h;
        h.x = max3f(lw_all, v.x, v.y);
        h.y = max3f(v.x, v.y, v.z);
        h.z = max3f(v.y, v.z, v.w);
        h.w = max3f(v.z, v.w, rx_all);
        return h;
    };

    // prologue: rows rel 0,1 and prefetch rel 2
    float4 v0 = *(const float4*)(rowp(0) + c0);
    float lw0 = 0.f, rx0 = 0.f;
    if (lane == 0) lw0 = rowp(0)[cl];
    if (lane == 63) rx0 = rowp(0)[cr];
    float4 v1 = *(const float4*)(rowp(1) + c0);
    float lw1 = 0.f, rx1 = 0.f;
    if (lane == 0) lw1 = rowp(1)[cl];
    if (lane == 63) rx1 = rowp(1)[cr];
    float4 vN = *(const float4*)(rowp(2) + c0);
    float lwN = 0.f, rxN = 0.f;
    if (lane == 0) lwN = rowp(2)[cl];
    if (lane == 63) rxN = rowp(2)[cr];

    float4 hA = mkhalo(v0, lw0, rx0);
    float4 hB = mkhalo(v1, lw1, rx1);
    float4 ctrB = v1;                        // center row values (cols c0..c0+3)

    unsigned cnt = 0;
#pragma unroll
    for (int i = 2; i <= SH + 1; ++i) {
        float4 v = vN;
        float lwc = lwN, rxc = rxN;
        vN = *(const float4*)(rowp(i + 1) + c0);   // depth-1 prefetch (clamped)
        lwN = 0.f; rxN = 0.f;
        if (lane == 0) lwN = rowp(i + 1)[cl];
        if (lane == 63) rxN = rowp(i + 1)[cr];

        float4 hC = mkhalo(v, lwc, rxc);

        const int yloc = ytile * SH + (i - 2);     // image-local y of emitted row
        unsigned nib = 0u;
        if (yloc >= 10 && yloc < H - 10) {
            nib |= (ctrB.x >= fmaxf(max3f(hA.x, hB.x, hC.x), REP_THR)) ? 1u : 0u;
            nib |= (ctrB.y >= fmaxf(max3f(hA.y, hB.y, hC.y), REP_THR)) ? 2u : 0u;
            nib |= (ctrB.z >= fmaxf(max3f(hA.z, hB.z, hC.z), REP_THR)) ? 4u : 0u;
            nib |= (ctrB.w >= fmaxf(max3f(hA.w, hB.w, hC.w), REP_THR)) ? 8u : 0u;
            nib &= colm;
        }
        cnt += __popc(nib);
        // fold 16 lanes' nibbles -> u64 chunk (lane%16==0 stores)
        unsigned x = nib;
        x |= __shfl_down(x, 1, 64) << 4;
        x |= __shfl_down(x, 2, 64) << 8;
        x |= __shfl_down(x, 4, 64) << 16;
        unsigned hi = __shfl_down(x, 8, 64);
        if ((lane & 15) == 0) {
            unsigned long long m64 = (unsigned long long)x | ((unsigned long long)hi << 32);
            masks[(size_t)(r0 + i - 2) * CPR + (t >> 4)] = m64;
        }
        hA = hB; hB = hC; ctrB = v;
    }

#pragma unroll
    for (int o = 32; o > 0; o >>= 1) cnt += __shfl_down(cnt, o, 64);
    __shared__ unsigned wsum[BLOCK1 / 64];
    if (lane == 0) wsum[wv] = cnt;
    __syncthreads();
    if (t == 0) {
        unsigned s = 0;
#pragma unroll
        for (int k = 0; k < BLOCK1 / 64; ++k) s += wsum[k];
        counts[blk] = s;
    }
}

// Pass 2: fused scan + scatter with LDS-staged coalesced output.
// One u64 chunk per thread (row-major => thread order == spatial order).
__global__ __launch_bounds__(BLOCK2) void nms_scatter(const unsigned long long* __restrict__ masks,
                                                      const unsigned int* __restrict__ counts,
                                                      int* __restrict__ out, unsigned int K) {
    __shared__ unsigned wtot[NW2];
    __shared__ unsigned sred[NW2];
    __shared__ unsigned pk[CAP];             // packed y | x<<16
    const int t = threadIdx.x, lane = t & 63, wv = t >> 6;
    const int blk = blockIdx.x;
    unsigned long long bits = masks[(size_t)blk * BLOCK2 + t];
    const unsigned cnt = (unsigned)__popcll(bits);
    unsigned incl = cnt;
#pragma unroll
    for (int o = 1; o < 64; o <<= 1) {
        unsigned u = __shfl_up(incl, o, 64);
        if (lane >= o) incl += u;
    }
    // exclusive block offset: sum of counts[0..blk) over 1024 pass1 counts
    unsigned part = 0;
    if (t < blk) part += counts[t];
    if (t + BLOCK2 < blk) part += counts[t + BLOCK2];
#pragma unroll
    for (int o = 32; o > 0; o >>= 1) part += __shfl_down(part, o, 64);
    if (lane == 63) wtot[wv] = incl;
    if (lane == 0) sred[wv] = part;
    __syncthreads();
    unsigned blockBase = 0, blockCnt = 0, wbase = 0;
#pragma unroll
    for (int k = 0; k < NW2; ++k) {
        blockBase += sred[k];
        blockCnt += wtot[k];
        if (k < wv) wbase += wtot[k];
    }
    unsigned local = wbase + (incl - cnt);   // block-local index of this thread's first item
    if (bits) {
        const int y = (blk % (H / SH)) * SH + t / CPR;   // image-local row
        const int x0 = (t % CPR) * 64;
        while (bits) {
            int j = __builtin_ctzll(bits);
            bits &= bits - 1ull;
            if (local < CAP) {
                pk[local] = (unsigned)y | ((unsigned)(x0 + j) << 16);
            } else {                          // overflow fallback (correct for any input)
                unsigned g = blockBase + local;
                if (g < K) { out[g] = y; out[K + g] = x0 + j; }
            }
            ++local;
        }
    }
    __syncthreads();
    const unsigned lim = blockCnt < CAP ? blockCnt : CAP;
    for (unsigned i = t; i < lim; i += BLOCK2) {
        unsigned g = blockBase + i;
        if (g < K) {
            unsigned p = pk[i];
            out[g] = (int)(p & 0xFFFFu);
            out[K + g] = (int)(p >> 16);
        }
    }
}

extern "C" void kernel_launch(void* const* d_in, const int* in_sizes, int n_in,
                              void* d_out, int out_size, void* d_ws, size_t ws_size,
                              hipStream_t stream) {
    const float* in = (const float*)d_in[0];
    int* out = (int*)d_out;
    unsigned long long* masks = (unsigned long long*)d_ws;
    unsigned int* counts = (unsigned int*)((char*)d_ws + (size_t)NMASK * 8);
    const unsigned K = (unsigned)(out_size / 2);

    nms_pass1<<<NBLK, BLOCK1, 0, stream>>>(in, masks, counts);
    nms_scatter<<<NBLK, BLOCK2, 0, stream>>>(masks, counts, out, K);
}